// Round 1
// baseline (956.326 us; speedup 1.0000x reference)
//
#include <hip/hip_runtime.h>

#define SEQ_LEN 96
#define PRED_LEN 16
#define HIDDEN 64
#define FEAT 7
#define BATCH 512
#define GATES 256          // 4*HIDDEN
#define TL (SEQ_LEN + PRED_LEN)  // 112-entry sliding timeline

__device__ __forceinline__ float sigmoidf_(float x) {
    return 1.0f / (1.0f + __expf(-x));
}
__device__ __forceinline__ float tanhf_(float x) {
    // tanh(x) = 1 - 2/(exp(2x)+1); exact at both saturation ends
    return 1.0f - 2.0f / (__expf(2.0f * x) + 1.0f);
}

// One block (256 threads) per batch element. Thread g owns gate g:
// W_hh row (64 fp32) + W_ih row (7 fp32) live in VGPRs; h, x-timeline,
// gate activations live in LDS (all reads are wave-broadcast -> conflict-free).
__global__ __launch_bounds__(256) void lstm_ar_kernel(
    const float* __restrict__ x,     // [B, 96, 7]
    const float* __restrict__ W_ih,  // [256, 7]
    const float* __restrict__ W_hh,  // [256, 64]
    const float* __restrict__ b_ih,  // [256]
    const float* __restrict__ b_hh,  // [256]
    const float* __restrict__ fc_W,  // [7, 64]
    const float* __restrict__ fc_b,  // [7]
    float* __restrict__ out)         // [B, 16, 7]
{
    __shared__ float xs[TL * FEAT];       // sliding input timeline (orig 96 + preds)
    __shared__ float hs[HIDDEN];          // hidden state
    __shared__ float gs[GATES];           // activated gates for current step
    __shared__ float fcw[FEAT * HIDDEN];  // fc weights
    __shared__ float fcb[FEAT];

    const int tid = threadIdx.x;
    const int b   = blockIdx.x;
    const int wv  = tid >> 6;             // wave id = gate class (i,f,g,o)

    // ---- per-thread weight registers ----
    float wih[FEAT];
    #pragma unroll
    for (int i = 0; i < FEAT; ++i) wih[i] = W_ih[tid * FEAT + i];
    const float bias = b_ih[tid] + b_hh[tid];

    float whh[HIDDEN];
    const float4* wrow = (const float4*)(W_hh + tid * HIDDEN);  // rows are 256B-aligned
    #pragma unroll
    for (int j = 0; j < HIDDEN / 4; ++j) {
        float4 v = wrow[j];
        whh[4*j+0] = v.x; whh[4*j+1] = v.y; whh[4*j+2] = v.z; whh[4*j+3] = v.w;
    }

    // ---- stage inputs / init state ----
    for (int i = tid; i < SEQ_LEN * FEAT; i += 256) xs[i] = x[b * SEQ_LEN * FEAT + i];
    for (int i = tid; i < FEAT * HIDDEN; i += 256) fcw[i] = fc_W[i];
    if (tid < FEAT)   fcb[tid] = fc_b[tid];
    if (tid < HIDDEN) hs[tid]  = 0.0f;
    float c = 0.0f;                       // cell state, owned by tid<64
    __syncthreads();

    for (int k = 0; k < PRED_LEN; ++k) {
        for (int t = 0; t < SEQ_LEN; ++t) {
            const float* xt = &xs[(k + t) * FEAT];

            float acc = bias;
            #pragma unroll
            for (int i = 0; i < FEAT; ++i) acc = fmaf(wih[i], xt[i], acc);

            const float4* h4 = (const float4*)hs;
            #pragma unroll
            for (int j = 0; j < HIDDEN / 4; ++j) {
                float4 hv = h4[j];
                acc = fmaf(whh[4*j+0], hv.x, acc);
                acc = fmaf(whh[4*j+1], hv.y, acc);
                acc = fmaf(whh[4*j+2], hv.z, acc);
                acc = fmaf(whh[4*j+3], hv.w, acc);
            }

            // PyTorch gate order i,f,g,o -> wave 2 is the tanh gate (wave-uniform branch)
            float act = (wv == 2) ? tanhf_(acc) : sigmoidf_(acc);
            gs[tid] = act;
            __syncthreads();              // gates visible; all hs reads of this step done

            if (tid < HIDDEN) {
                float ig = gs[tid];
                float fg = gs[HIDDEN     + tid];
                float gg = gs[2 * HIDDEN + tid];
                float og = gs[3 * HIDDEN + tid];
                c = fmaf(fg, c, ig * gg);
                hs[tid] = og * tanhf_(c);
            }
            __syncthreads();              // new h visible for next step
        }

        // ---- prediction head + append to timeline ----
        if (tid < FEAT) {
            float p = fcb[tid];
            #pragma unroll
            for (int j = 0; j < HIDDEN; ++j) p = fmaf(fcw[tid * HIDDEN + j], hs[j], p);
            out[(b * PRED_LEN + k) * FEAT + tid] = p;
            xs[(SEQ_LEN + k) * FEAT + tid] = p;
        }
        __syncthreads();                  // pred appended before it can be consumed
    }
}

extern "C" void kernel_launch(void* const* d_in, const int* in_sizes, int n_in,
                              void* d_out, int out_size, void* d_ws, size_t ws_size,
                              hipStream_t stream) {
    const float* x    = (const float*)d_in[0];
    const float* W_ih = (const float*)d_in[1];
    const float* W_hh = (const float*)d_in[2];
    const float* b_ih = (const float*)d_in[3];
    const float* b_hh = (const float*)d_in[4];
    const float* fc_W = (const float*)d_in[5];
    const float* fc_b = (const float*)d_in[6];
    float* out = (float*)d_out;

    lstm_ar_kernel<<<BATCH, 256, 0, stream>>>(x, W_ih, W_hh, b_ih, b_hh, fc_W, fc_b, out);
}